// Round 2
// baseline (235.475 us; speedup 1.0000x reference)
//
#include <hip/hip_runtime.h>
#include <hip/hip_bf16.h>

typedef short short8 __attribute__((ext_vector_type(8)));
typedef float f32x4 __attribute__((ext_vector_type(4)));

// LDS layout (byte offsets), peak 79360 B -> 2 blocks/CU (160 KiB/CU).
//  XN  [0,64K)       xn^T bf16 [w][c], alive P2->P3
//  AT  [0,32K)       attention A bf16 [w][v], aliases XN after P3
//  YTH [32K,64K)     Y^T half bf16 [w][c'], aliases XN after P3
//  GB  [64K,72K)     G band bf16 [v][o'] (32 cols), alive only inside P3
//  stats scratch [72K, 77.5K)
#define XN 0
#define AT 0
#define YTH 32768
#define GB 65536
#define SUMO 73728
#define SQO 75776
#define MUO 77824
#define RSO 78336
#define UDO 78848
#define LDS_BYTES 79360

__device__ inline unsigned short cvtbf(float f){
  unsigned int x = __float_as_uint(f);
  x += 0x7fffu + ((x >> 16) & 1u);           // RNE
  return (unsigned short)(x >> 16);
}
__device__ inline float bf2f(unsigned short u){ return __uint_as_float(((unsigned int)u) << 16); }
__device__ inline unsigned int pk2(float a, float b){ return (unsigned int)cvtbf(a) | ((unsigned int)cvtbf(b) << 16); }

// setup: M = wq^T wk (bf16), wv -> bf16, u = wk^T bq. 64 blocks x 4 rows each.
__global__ void __launch_bounds__(256) setup_kernel(
    const float* __restrict__ wq, const float* __restrict__ bq,
    const float* __restrict__ wk, const float* __restrict__ wvw,
    unsigned short* __restrict__ Mbf, unsigned short* __restrict__ wvbf, float* __restrict__ u){
  int t = threadIdx.x;
  int c1b = blockIdx.x * 4;
  float acc[4] = {0.f,0.f,0.f,0.f};
  for (int o = 0; o < 256; ++o){
    float wkv = wk[o*256 + t];
    #pragma unroll
    for (int i = 0; i < 4; ++i) acc[i] = fmaf(wq[o*256 + c1b + i], wkv, acc[i]);
  }
  #pragma unroll
  for (int i = 0; i < 4; ++i){
    Mbf[(c1b+i)*256 + t] = cvtbf(acc[i]);
    wvbf[(c1b+i)*256 + t] = cvtbf(wvw[(c1b+i)*256 + t]);
  }
  if (blockIdx.x == 0){
    float a2 = 0.f;
    for (int o = 0; o < 256; ++o) a2 = fmaf(wk[o*256 + t], bq[o], a2);
    u[t] = a2;
  }
}

__global__ void __launch_bounds__(512, 4) fused_kernel(
    const float* __restrict__ x, const float* __restrict__ nw, const float* __restrict__ nbp,
    const float* __restrict__ bvv, const float* __restrict__ beta,
    const unsigned short* __restrict__ Mbf, const unsigned short* __restrict__ wvbf,
    const float* __restrict__ u, float* __restrict__ out){
  extern __shared__ char smem[];
  const int t = threadIdx.x;
  const int lane = t & 63, wv8 = t >> 6;      // 8 waves
  const int g = lane >> 4, li = lane & 15;
  const int blk = blockIdx.x;
  const int b = blk >> 7, h = blk & 127;
  const size_t base = (size_t)b*4194304 + (size_t)h*128;  // x[b,c,h,w] = base + c*16384 + w

  // ---- P1: load x column-slice from global (coalesced across w), stats + keep bf16 in regs
  const int w = t & 127, s = t >> 7;          // this thread: spatial w, c-quarter s
  unsigned int xp[32];
  {
    const float* xw = x + base + (size_t)(s*64)*16384 + w;
    float sm = 0.f, sq = 0.f;
    #pragma unroll
    for (int j = 0; j < 32; ++j){
      float a0 = xw[(size_t)(2*j)*16384];
      float a1 = xw[(size_t)(2*j+1)*16384];
      sm += a0 + a1;
      sq = fmaf(a0, a0, sq); sq = fmaf(a1, a1, sq);
      xp[j] = pk2(a0, a1);
    }
    ((float*)(smem + SUMO))[s*128 + w] = sm;
    ((float*)(smem + SQO))[s*128 + w] = sq;
  }
  __syncthreads();
  if (t < 128){
    float sm = 0.f, sq = 0.f;
    for (int q = 0; q < 4; ++q){ sm += ((float*)(smem+SUMO))[q*128+t]; sq += ((float*)(smem+SQO))[q*128+t]; }
    float mu = sm * (1.f/256.f);
    float var = sq * (1.f/256.f) - mu*mu;
    ((float*)(smem+MUO))[t] = mu;
    ((float*)(smem+RSO))[t] = rsqrtf(var + 1e-6f);
  }
  __syncthreads();

  // ---- P2: xn^T [w][c] from registers; udot partials
  {
    float mu = ((float*)(smem+MUO))[w], rs = ((float*)(smem+RSO))[w];
    float ud = 0.f;
    #pragma unroll
    for (int i = 0; i < 8; ++i){
      int c0 = s*64 + i*8;
      short8 o8;
      #pragma unroll
      for (int j = 0; j < 4; ++j){
        unsigned int p = xp[i*4 + j];
        int c = c0 + j*2;
        float xa = bf2f((unsigned short)(p & 0xffffu));
        float xb = bf2f((unsigned short)(p >> 16));
        float na = (xa - mu)*rs*nw[c]   + nbp[c];
        float nbv = (xb - mu)*rs*nw[c+1] + nbp[c+1];
        ud = fmaf(u[c], na, fmaf(u[c+1], nbv, ud));
        o8[j*2]   = (short)cvtbf(na);
        o8[j*2+1] = (short)cvtbf(nbv);
      }
      *(short8*)(smem + XN + w*512 + ((2*c0) ^ ((w&7)<<4))) = o8;
    }
    ((float*)(smem+SUMO))[s*128 + w] = ud;
  }
  __syncthreads();
  if (t < 128){
    float ud = 0.f; for (int q = 0; q < 4; ++q) ud += ((float*)(smem+SUMO))[q*128+t];
    ((float*)(smem+UDO))[t] = ud;
  }
  __syncthreads();

  // ---- P3: S^T[v][w] = sum_o G[o][v]*xn[o][w] (+udot[v]), G in 32-row bands
  f32x4 Sacc[8];
  #pragma unroll
  for (int vt = 0; vt < 8; ++vt){
    int vb = vt*16 + g*4;
    #pragma unroll
    for (int r = 0; r < 4; ++r) Sacc[vt][r] = ((float*)(smem+UDO))[vb + r];
  }
  const int ot = wv8 >> 2, vp = wv8 & 3;
  const int wt = wv8;
  for (int k8 = 0; k8 < 8; ++k8){
    // G band: this wave does 16 o' x 32 v
    f32x4 Ga[2] = {{0.f,0.f,0.f,0.f},{0.f,0.f,0.f,0.f}};
    #pragma unroll
    for (int kk = 0; kk < 8; ++kk){
      int o = k8*32 + ot*16 + li;
      short8 afr = *(const short8*)(Mbf + o*256 + kk*32 + g*8);
      #pragma unroll
      for (int j = 0; j < 2; ++j){
        int v = (vp*2 + j)*16 + li;
        short8 bfr = *(const short8*)(smem + XN + v*512 + ((2*(kk*32 + g*8)) ^ ((v&7)<<4)));
        Ga[j] = __builtin_amdgcn_mfma_f32_16x16x32_bf16(afr, bfr, Ga[j], 0, 0, 0);
      }
    }
    __syncthreads();  // prev chunk's S reads of GB complete
    #pragma unroll
    for (int j = 0; j < 2; ++j){
      int v = (vp*2 + j)*16 + li;
      int ob = ot*16 + g*4;
      uint2 p; p.x = pk2(Ga[j][0], Ga[j][1]); p.y = pk2(Ga[j][2], Ga[j][3]);
      *(uint2*)(smem + GB + v*64 + ((2*ob) ^ ((v&3)<<4))) = p;
    }
    __syncthreads();
    // S accumulation: this wave owns w-tile wt (all v)
    {
      int ww = wt*16 + li;
      short8 bfr = *(const short8*)(smem + XN + ww*512 + ((2*(k8*32 + g*8)) ^ ((ww&7)<<4)));
      #pragma unroll
      for (int vt = 0; vt < 8; ++vt){
        int v = vt*16 + li;
        short8 afr = *(const short8*)(smem + GB + v*64 + ((16*g) ^ ((v&3)<<4)));
        Sacc[vt] = __builtin_amdgcn_mfma_f32_16x16x32_bf16(afr, bfr, Sacc[vt], 0, 0, 0);
      }
    }
  }
  __syncthreads();

  // ---- softmax over v (rows of S^T): in-lane 32 vals + xor16/32
  float mx = -3.4e38f;
  #pragma unroll
  for (int vt = 0; vt < 8; ++vt)
    #pragma unroll
    for (int r = 0; r < 4; ++r){ float sv = Sacc[vt][r]*0.0625f; Sacc[vt][r] = sv; mx = fmaxf(mx, sv); }
  mx = fmaxf(mx, __shfl_xor(mx, 16));
  mx = fmaxf(mx, __shfl_xor(mx, 32));
  float sum = 0.f;
  #pragma unroll
  for (int vt = 0; vt < 8; ++vt)
    #pragma unroll
    for (int r = 0; r < 4; ++r){ float p = exp2f((Sacc[vt][r]-mx)*1.44269504f); Sacc[vt][r] = p; sum += p; }
  sum += __shfl_xor(sum, 16);
  sum += __shfl_xor(sum, 32);
  float inv = 1.f / sum;
  {
    int ww = wt*16 + li;
    #pragma unroll
    for (int vt = 0; vt < 8; ++vt){
      uint2 p; p.x = pk2(Sacc[vt][0]*inv, Sacc[vt][1]*inv); p.y = pk2(Sacc[vt][2]*inv, Sacc[vt][3]*inv);
      int vb = vt*16 + g*4;
      *(uint2*)(smem + AT + ww*256 + ((2*vb) ^ ((ww&7)<<4))) = p;
    }
  }
  __syncthreads();

  // ---- P4: Y[c][w] = sum_v x[c][v] * A[w][v]; x A-frags straight from global (L2-hot)
  f32x4 Yacc[2][8];
  #pragma unroll
  for (int ci = 0; ci < 2; ++ci)
    #pragma unroll
    for (int w2 = 0; w2 < 8; ++w2) Yacc[ci][w2] = (f32x4){0.f,0.f,0.f,0.f};
  #pragma unroll
  for (int kk = 0; kk < 4; ++kk){
    short8 afr[2];
    #pragma unroll
    for (int ci = 0; ci < 2; ++ci){
      int c = (wv8*2 + ci)*16 + li;
      const float* xs = x + base + (size_t)c*16384 + (kk*32 + g*8);
      const float4 f0 = *(const float4*)xs;
      const float4 f1 = *(const float4*)(xs + 4);
      short8 a;
      a[0]=(short)cvtbf(f0.x); a[1]=(short)cvtbf(f0.y); a[2]=(short)cvtbf(f0.z); a[3]=(short)cvtbf(f0.w);
      a[4]=(short)cvtbf(f1.x); a[5]=(short)cvtbf(f1.y); a[6]=(short)cvtbf(f1.z); a[7]=(short)cvtbf(f1.w);
      afr[ci] = a;
    }
    #pragma unroll
    for (int w2 = 0; w2 < 8; ++w2){
      int ww = w2*16 + li;
      short8 bfr = *(const short8*)(smem + AT + ww*256 + ((2*(kk*32 + g*8)) ^ ((ww&7)<<4)));
      #pragma unroll
      for (int ci = 0; ci < 2; ++ci)
        Yacc[ci][w2] = __builtin_amdgcn_mfma_f32_16x16x32_bf16(afr[ci], bfr, Yacc[ci][w2], 0, 0, 0);
    }
  }

  // ---- P5: F[o][w] = sum_c wv[o][c] Y[c][w], c in two 128-halves through 32KB YTH
  f32x4 Facc[2][8];
  #pragma unroll
  for (int oi = 0; oi < 2; ++oi)
    #pragma unroll
    for (int w2 = 0; w2 < 8; ++w2) Facc[oi][w2] = (f32x4){0.f,0.f,0.f,0.f};
  for (int half = 0; half < 2; ++half){
    if ((wv8 >> 2) == half){
      #pragma unroll
      for (int ci = 0; ci < 2; ++ci){
        int cb = ((wv8 & 3)*2 + ci)*16 + g*4;   // c' within half
        #pragma unroll
        for (int w2 = 0; w2 < 8; ++w2){
          int ww = w2*16 + li;
          uint2 p; p.x = pk2(Yacc[ci][w2][0], Yacc[ci][w2][1]); p.y = pk2(Yacc[ci][w2][2], Yacc[ci][w2][3]);
          *(uint2*)(smem + YTH + ww*256 + ((2*cb) ^ ((ww&7)<<4))) = p;
        }
      }
    }
    __syncthreads();
    #pragma unroll
    for (int kk = 0; kk < 4; ++kk){
      short8 afr[2];
      #pragma unroll
      for (int oi = 0; oi < 2; ++oi){
        int o = (wv8*2 + oi)*16 + li;
        afr[oi] = *(const short8*)(wvbf + o*256 + half*128 + kk*32 + g*8);
      }
      #pragma unroll
      for (int w2 = 0; w2 < 8; ++w2){
        int ww = w2*16 + li;
        short8 bfr = *(const short8*)(smem + YTH + ww*256 + ((2*(kk*32 + g*8)) ^ ((ww&7)<<4)));
        #pragma unroll
        for (int oi = 0; oi < 2; ++oi)
          Facc[oi][w2] = __builtin_amdgcn_mfma_f32_16x16x32_bf16(afr[oi], bfr, Facc[oi][w2], 0, 0, 0);
      }
    }
    __syncthreads();
  }

  // ---- epilogue: out = x + (F + bv)*beta
  #pragma unroll
  for (int oi = 0; oi < 2; ++oi){
    #pragma unroll
    for (int r = 0; r < 4; ++r){
      int o = (wv8*2 + oi)*16 + g*4 + r;
      float bvo = bvv[o], bto = beta[o];
      #pragma unroll
      for (int w2 = 0; w2 < 8; ++w2){
        int ww = w2*16 + li;
        size_t idx = base + (size_t)o*16384 + (size_t)ww;
        out[idx] = x[idx] + (Facc[oi][w2][r] + bvo)*bto;
      }
    }
  }
}

extern "C" void kernel_launch(void* const* d_in, const int* in_sizes, int n_in,
                              void* d_out, int out_size, void* d_ws, size_t ws_size,
                              hipStream_t stream) {
  (void)in_sizes; (void)n_in; (void)out_size; (void)ws_size;
  const float* x      = (const float*)d_in[0];
  const float* norm_w = (const float*)d_in[1];
  const float* norm_b = (const float*)d_in[2];
  const float* wq     = (const float*)d_in[3];
  const float* bq     = (const float*)d_in[4];
  const float* wk     = (const float*)d_in[5];
  // d_in[6] = bk: only enters softmax-invariant terms, mathematically dropped
  const float* wvw    = (const float*)d_in[7];
  const float* bvv    = (const float*)d_in[8];
  const float* beta   = (const float*)d_in[9];
  float* out = (float*)d_out;

  unsigned short* Mbf  = (unsigned short*)d_ws;                    // 128 KB
  unsigned short* wvbf = (unsigned short*)((char*)d_ws + 131072);  // 128 KB
  float* u             = (float*)((char*)d_ws + 262144);           // 1 KB

  static bool attr_set = false;
  if (!attr_set) {
    (void)hipFuncSetAttribute((const void*)fused_kernel,
                              hipFuncAttributeMaxDynamicSharedMemorySize, LDS_BYTES);
    attr_set = true;
  }

  setup_kernel<<<64, 256, 0, stream>>>(wq, bq, wk, wvw, Mbf, wvbf, u);
  fused_kernel<<<1024, 512, LDS_BYTES, stream>>>(x, norm_w, norm_b, bvv, beta, Mbf, wvbf, u, out);
}

// Round 3
// 209.381 us; speedup vs baseline: 1.1246x; 1.1246x over previous
//
#include <hip/hip_runtime.h>
#include <hip/hip_bf16.h>

typedef short short8 __attribute__((ext_vector_type(8)));
typedef float f32x4 __attribute__((ext_vector_type(4)));

// LDS layout (byte offsets), total 78336 -> 2 blocks/CU.
//  XN  [0,64K)        xn^T bf16 [w][c], alive P2->P3
//  AT  [0,32K)        attention A bf16 [w][v], aliases XN after P3
//  YTH [32K,64K)      Y^T half bf16 [w][c'], aliases XN after P3
//  GB  [64K,72K)      G band bf16 [v][o'] (32 cols), alive only inside P3
//  STATS [64K,72K)    sm/sq/ud partials [8][128] f32, overlays GB (dead til P3)
//  NW/NB/UU [72K..75K) norm params staged once
//  MUO/RSO/UDO        per-w scalars
#define XN 0
#define AT 0
#define YTH 32768
#define GB 65536
#define SUMO 65536
#define SQO 69632
#define NW 73728
#define NB 74752
#define UU 75776
#define MUO 76800
#define RSO 77312
#define UDO 77824
#define LDS_BYTES 78336

__device__ inline unsigned short cvtbf(float f){
  unsigned int x = __float_as_uint(f);
  x += 0x7fffu + ((x >> 16) & 1u);           // RNE
  return (unsigned short)(x >> 16);
}
__device__ inline float bf2f(unsigned short u){ return __uint_as_float(((unsigned int)u) << 16); }
__device__ inline unsigned int pk2(float a, float b){ return (unsigned int)cvtbf(a) | ((unsigned int)cvtbf(b) << 16); }

// setup: M = wq^T wk (bf16), wv -> bf16, u = wk^T bq. 64 blocks x 4 rows each.
__global__ void __launch_bounds__(256) setup_kernel(
    const float* __restrict__ wq, const float* __restrict__ bq,
    const float* __restrict__ wk, const float* __restrict__ wvw,
    unsigned short* __restrict__ Mbf, unsigned short* __restrict__ wvbf, float* __restrict__ u){
  int t = threadIdx.x;
  int c1b = blockIdx.x * 4;
  float acc[4] = {0.f,0.f,0.f,0.f};
  for (int o = 0; o < 256; ++o){
    float wkv = wk[o*256 + t];
    #pragma unroll
    for (int i = 0; i < 4; ++i) acc[i] = fmaf(wq[o*256 + c1b + i], wkv, acc[i]);
  }
  #pragma unroll
  for (int i = 0; i < 4; ++i){
    Mbf[(c1b+i)*256 + t] = cvtbf(acc[i]);
    wvbf[(c1b+i)*256 + t] = cvtbf(wvw[(c1b+i)*256 + t]);
  }
  if (blockIdx.x == 0){
    float a2 = 0.f;
    for (int o = 0; o < 256; ++o) a2 = fmaf(wk[o*256 + t], bq[o], a2);
    u[t] = a2;
  }
}

__global__ void __launch_bounds__(512, 4) fused_kernel(
    const float* __restrict__ x, const float* __restrict__ nw, const float* __restrict__ nbp,
    const float* __restrict__ bvv, const float* __restrict__ beta,
    const unsigned short* __restrict__ Mbf, const unsigned short* __restrict__ wvbf,
    const float* __restrict__ u, float* __restrict__ out){
  extern __shared__ char smem[];
  const int t = threadIdx.x;
  const int lane = t & 63, wv8 = t >> 6;      // 8 waves
  const int g = lane >> 4, li = lane & 15;
  const int blk = blockIdx.x;
  const int b = blk >> 7, h = blk & 127;
  const size_t base = (size_t)b*4194304 + (size_t)h*128;  // x[b,c,h,w] = base + c*16384 + w

  // ---- P0: stage norm params (256 floats x3) into LDS
  if (t < 256){
    ((float*)(smem + NW))[t] = nw[t];
    ((float*)(smem + NB))[t] = nbp[t];
    ((float*)(smem + UU))[t] = u[t];
  }

  // ---- P1: load x column-pairs from global (coalesced float2 across w), per-w stats
  const int w2 = t & 63, s = t >> 6;          // w-pair index, c-octant (32 c's)
  unsigned int xp[32];                         // [c-idx] packed bf16 (w, w+1)
  {
    const float* xw = x + base + (size_t)(s*32)*16384 + 2*w2;
    float sm0 = 0.f, sq0 = 0.f, sm1 = 0.f, sq1 = 0.f;
    #pragma unroll
    for (int j = 0; j < 32; ++j){
      float2 v = *(const float2*)(xw + (size_t)j*16384);
      sm0 += v.x; sq0 = fmaf(v.x, v.x, sq0);
      sm1 += v.y; sq1 = fmaf(v.y, v.y, sq1);
      xp[j] = pk2(v.x, v.y);
    }
    ((float*)(smem + SUMO))[s*128 + 2*w2]     = sm0;
    ((float*)(smem + SUMO))[s*128 + 2*w2 + 1] = sm1;
    ((float*)(smem + SQO))[s*128 + 2*w2]      = sq0;
    ((float*)(smem + SQO))[s*128 + 2*w2 + 1]  = sq1;
  }
  __syncthreads();
  if (t < 128){
    float sm = 0.f, sq = 0.f;
    #pragma unroll
    for (int q = 0; q < 8; ++q){ sm += ((float*)(smem+SUMO))[q*128+t]; sq += ((float*)(smem+SQO))[q*128+t]; }
    float mu = sm * (1.f/256.f);
    float var = sq * (1.f/256.f) - mu*mu;
    ((float*)(smem+MUO))[t] = mu;
    ((float*)(smem+RSO))[t] = rsqrtf(var + 1e-6f);
  }
  __syncthreads();

  // ---- P2: xn^T [w][c] from registers (2 rows per thread); udot partials
  {
    float ud[2] = {0.f, 0.f};
    #pragma unroll
    for (int r = 0; r < 2; ++r){
      int w = 2*w2 + r;
      float mu = ((float*)(smem+MUO))[w], rs = ((float*)(smem+RSO))[w];
      #pragma unroll
      for (int i = 0; i < 4; ++i){
        int c0 = s*32 + i*8;
        short8 o8;
        #pragma unroll
        for (int j = 0; j < 8; ++j){
          int c = c0 + j;
          unsigned int p = xp[i*8 + j];
          float xv = bf2f((unsigned short)(r ? (p >> 16) : (p & 0xffffu)));
          float nv = (xv - mu)*rs*((float*)(smem+NW))[c] + ((float*)(smem+NB))[c];
          ud[r] = fmaf(((float*)(smem+UU))[c], nv, ud[r]);
          o8[j] = (short)cvtbf(nv);
        }
        *(short8*)(smem + XN + w*512 + ((2*c0) ^ ((w&31)<<4))) = o8;
      }
    }
    __syncthreads();   // SUMO partial-sum reads (t<128) done; safe to overwrite with ud
    ((float*)(smem+SUMO))[s*128 + 2*w2]     = ud[0];
    ((float*)(smem+SUMO))[s*128 + 2*w2 + 1] = ud[1];
  }
  __syncthreads();
  if (t < 128){
    float ud = 0.f;
    #pragma unroll
    for (int q = 0; q < 8; ++q) ud += ((float*)(smem+SUMO))[q*128+t];
    ((float*)(smem+UDO))[t] = ud;
  }
  __syncthreads();

  // ---- P3: S^T[v][w] = sum_o G[o][v]*xn[o][w] (+udot[v]), G in 32-row bands
  f32x4 Sacc[8];
  #pragma unroll
  for (int vt = 0; vt < 8; ++vt){
    int vb = vt*16 + g*4;
    #pragma unroll
    for (int r = 0; r < 4; ++r) Sacc[vt][r] = ((float*)(smem+UDO))[vb + r];
  }
  const int ot = wv8 >> 2, vp = wv8 & 3;
  const int wt = wv8;
  // prime M prefetch for k8=0, kk=0..3 (registers survive barriers)
  short8 mpre[4];
  #pragma unroll
  for (int kk = 0; kk < 4; ++kk)
    mpre[kk] = *(const short8*)(Mbf + (ot*16 + li)*256 + kk*32 + g*8);
  #pragma unroll
  for (int k8 = 0; k8 < 8; ++k8){
    // G band: this wave does 16 o' x 32 v
    f32x4 Ga[2] = {{0.f,0.f,0.f,0.f},{0.f,0.f,0.f,0.f}};
    const int o = k8*32 + ot*16 + li;
    short8 mnext[4];
    __builtin_amdgcn_s_setprio(1);
    #pragma unroll
    for (int kk = 0; kk < 8; ++kk){
      short8 afr = (kk < 4) ? mpre[kk]
                 : *(const short8*)(Mbf + o*256 + kk*32 + g*8);
      if (kk < 4 && k8 < 7){
        // prefetch next band's first-half A-frags across the upcoming barriers
        mnext[kk] = *(const short8*)(Mbf + ((k8+1)*32 + ot*16 + li)*256 + kk*32 + g*8);
      }
      #pragma unroll
      for (int j = 0; j < 2; ++j){
        int v = (vp*2 + j)*16 + li;
        short8 bfr = *(const short8*)(smem + XN + v*512 + ((2*(kk*32 + g*8)) ^ ((v&31)<<4)));
        Ga[j] = __builtin_amdgcn_mfma_f32_16x16x32_bf16(afr, bfr, Ga[j], 0, 0, 0);
      }
    }
    __builtin_amdgcn_s_setprio(0);
    #pragma unroll
    for (int kk = 0; kk < 4; ++kk) mpre[kk] = mnext[kk];
    __syncthreads();  // prev band's S reads of GB complete
    #pragma unroll
    for (int j = 0; j < 2; ++j){
      int v = (vp*2 + j)*16 + li;
      int ob = ot*16 + g*4;
      uint2 p; p.x = pk2(Ga[j][0], Ga[j][1]); p.y = pk2(Ga[j][2], Ga[j][3]);
      *(uint2*)(smem + GB + v*64 + ((2*ob) ^ ((v&3)<<4))) = p;
    }
    __syncthreads();
    // S accumulation: this wave owns w-tile wt (all v)
    {
      int ww = wt*16 + li;
      short8 bfr = *(const short8*)(smem + XN + ww*512 + ((2*(k8*32 + g*8)) ^ ((ww&31)<<4)));
      __builtin_amdgcn_s_setprio(1);
      #pragma unroll
      for (int vt = 0; vt < 8; ++vt){
        int v = vt*16 + li;
        short8 afr = *(const short8*)(smem + GB + v*64 + ((16*g) ^ ((v&3)<<4)));
        Sacc[vt] = __builtin_amdgcn_mfma_f32_16x16x32_bf16(afr, bfr, Sacc[vt], 0, 0, 0);
      }
      __builtin_amdgcn_s_setprio(0);
    }
  }
  __syncthreads();

  // ---- P4 prefetch: issue x loads for kk=0,1 now; softmax VALU + barrier hides latency
  float4 xe[2][2][2];  // [kk-buf][ci][half]
  #pragma unroll
  for (int kb = 0; kb < 2; ++kb)
    #pragma unroll
    for (int ci = 0; ci < 2; ++ci){
      int c = (wv8*2 + ci)*16 + li;
      const float* xs = x + base + (size_t)c*16384 + (kb*32 + g*8);
      xe[kb][ci][0] = *(const float4*)xs;
      xe[kb][ci][1] = *(const float4*)(xs + 4);
    }

  // ---- softmax over v (rows of S^T): in-lane 32 vals + xor16/32
  float mx = -3.4e38f;
  #pragma unroll
  for (int vt = 0; vt < 8; ++vt)
    #pragma unroll
    for (int r = 0; r < 4; ++r){ float sv = Sacc[vt][r]*0.0625f; Sacc[vt][r] = sv; mx = fmaxf(mx, sv); }
  mx = fmaxf(mx, __shfl_xor(mx, 16));
  mx = fmaxf(mx, __shfl_xor(mx, 32));
  float sum = 0.f;
  #pragma unroll
  for (int vt = 0; vt < 8; ++vt)
    #pragma unroll
    for (int r = 0; r < 4; ++r){ float p = exp2f((Sacc[vt][r]-mx)*1.44269504f); Sacc[vt][r] = p; sum += p; }
  sum += __shfl_xor(sum, 16);
  sum += __shfl_xor(sum, 32);
  float inv = 1.f / sum;
  {
    int ww = wt*16 + li;
    #pragma unroll
    for (int vt = 0; vt < 8; ++vt){
      uint2 p; p.x = pk2(Sacc[vt][0]*inv, Sacc[vt][1]*inv); p.y = pk2(Sacc[vt][2]*inv, Sacc[vt][3]*inv);
      int vb = vt*16 + g*4;
      *(uint2*)(smem + AT + ww*256 + ((2*vb) ^ ((ww&15)<<4))) = p;
    }
  }
  __syncthreads();

  // ---- P4: Y[c][w] = sum_v x[c][v] * A[w][v]; x A-frags 2-deep pipelined from global
  f32x4 Yacc[2][8];
  #pragma unroll
  for (int ci = 0; ci < 2; ++ci)
    #pragma unroll
    for (int w2i = 0; w2i < 8; ++w2i) Yacc[ci][w2i] = (f32x4){0.f,0.f,0.f,0.f};
  #pragma unroll
  for (int kk = 0; kk < 4; ++kk){
    short8 afr[2];
    #pragma unroll
    for (int ci = 0; ci < 2; ++ci){
      const float4 f0 = xe[kk&1][ci][0];
      const float4 f1 = xe[kk&1][ci][1];
      short8 a;
      a[0]=(short)cvtbf(f0.x); a[1]=(short)cvtbf(f0.y); a[2]=(short)cvtbf(f0.z); a[3]=(short)cvtbf(f0.w);
      a[4]=(short)cvtbf(f1.x); a[5]=(short)cvtbf(f1.y); a[6]=(short)cvtbf(f1.z); a[7]=(short)cvtbf(f1.w);
      afr[ci] = a;
    }
    if (kk < 2){
      #pragma unroll
      for (int ci = 0; ci < 2; ++ci){
        int c = (wv8*2 + ci)*16 + li;
        const float* xs = x + base + (size_t)c*16384 + ((kk+2)*32 + g*8);
        xe[kk&1][ci][0] = *(const float4*)xs;
        xe[kk&1][ci][1] = *(const float4*)(xs + 4);
      }
    }
    __builtin_amdgcn_s_setprio(1);
    #pragma unroll
    for (int w2i = 0; w2i < 8; ++w2i){
      int ww = w2i*16 + li;
      short8 bfr = *(const short8*)(smem + AT + ww*256 + ((2*(kk*32 + g*8)) ^ ((ww&15)<<4)));
      #pragma unroll
      for (int ci = 0; ci < 2; ++ci)
        Yacc[ci][w2i] = __builtin_amdgcn_mfma_f32_16x16x32_bf16(afr[ci], bfr, Yacc[ci][w2i], 0, 0, 0);
    }
    __builtin_amdgcn_s_setprio(0);
  }

  // ---- P5: F[o][w] = sum_c wv[o][c] Y[c][w], c in two 128-halves through 32KB YTH
  f32x4 Facc[2][8];
  #pragma unroll
  for (int oi = 0; oi < 2; ++oi)
    #pragma unroll
    for (int w2i = 0; w2i < 8; ++w2i) Facc[oi][w2i] = (f32x4){0.f,0.f,0.f,0.f};
  #pragma unroll
  for (int half = 0; half < 2; ++half){
    if ((wv8 >> 2) == half){
      #pragma unroll
      for (int ci = 0; ci < 2; ++ci){
        int cb = ((wv8 & 3)*2 + ci)*16 + g*4;   // c' within half
        #pragma unroll
        for (int w2i = 0; w2i < 8; ++w2i){
          int ww = w2i*16 + li;
          uint2 p; p.x = pk2(Yacc[ci][w2i][0], Yacc[ci][w2i][1]); p.y = pk2(Yacc[ci][w2i][2], Yacc[ci][w2i][3]);
          *(uint2*)(smem + YTH + ww*256 + ((2*cb) ^ ((ww&15)<<4))) = p;
        }
      }
    }
    __syncthreads();
    #pragma unroll
    for (int kk = 0; kk < 4; ++kk){
      short8 afr[2];
      #pragma unroll
      for (int oi = 0; oi < 2; ++oi){
        int o = (wv8*2 + oi)*16 + li;
        afr[oi] = *(const short8*)(wvbf + o*256 + half*128 + kk*32 + g*8);
      }
      __builtin_amdgcn_s_setprio(1);
      #pragma unroll
      for (int w2i = 0; w2i < 8; ++w2i){
        int ww = w2i*16 + li;
        short8 bfr = *(const short8*)(smem + YTH + ww*256 + ((2*(kk*32 + g*8)) ^ ((ww&15)<<4)));
        #pragma unroll
        for (int oi = 0; oi < 2; ++oi)
          Facc[oi][w2i] = __builtin_amdgcn_mfma_f32_16x16x32_bf16(afr[oi], bfr, Facc[oi][w2i], 0, 0, 0);
      }
      __builtin_amdgcn_s_setprio(0);
    }
    __syncthreads();
  }

  // ---- epilogue: out = x + (F + bv)*beta
  #pragma unroll
  for (int oi = 0; oi < 2; ++oi){
    #pragma unroll
    for (int r = 0; r < 4; ++r){
      int o = (wv8*2 + oi)*16 + g*4 + r;
      float bvo = bvv[o], bto = beta[o];
      #pragma unroll
      for (int w2i = 0; w2i < 8; ++w2i){
        int ww = w2i*16 + li;
        size_t idx = base + (size_t)o*16384 + (size_t)ww;
        out[idx] = x[idx] + (Facc[oi][w2i][r] + bvo)*bto;
      }
    }
  }
}

extern "C" void kernel_launch(void* const* d_in, const int* in_sizes, int n_in,
                              void* d_out, int out_size, void* d_ws, size_t ws_size,
                              hipStream_t stream) {
  (void)in_sizes; (void)n_in; (void)out_size; (void)ws_size;
  const float* x      = (const float*)d_in[0];
  const float* norm_w = (const float*)d_in[1];
  const float* norm_b = (const float*)d_in[2];
  const float* wq     = (const float*)d_in[3];
  const float* bq     = (const float*)d_in[4];
  const float* wk     = (const float*)d_in[5];
  // d_in[6] = bk: only enters softmax-invariant terms, mathematically dropped
  const float* wvw    = (const float*)d_in[7];
  const float* bvv    = (const float*)d_in[8];
  const float* beta   = (const float*)d_in[9];
  float* out = (float*)d_out;

  unsigned short* Mbf  = (unsigned short*)d_ws;                    // 128 KB
  unsigned short* wvbf = (unsigned short*)((char*)d_ws + 131072);  // 128 KB
  float* u             = (float*)((char*)d_ws + 262144);           // 1 KB

  static bool attr_set = false;
  if (!attr_set) {
    (void)hipFuncSetAttribute((const void*)fused_kernel,
                              hipFuncAttributeMaxDynamicSharedMemorySize, LDS_BYTES);
    attr_set = true;
  }

  setup_kernel<<<64, 256, 0, stream>>>(wq, bq, wk, wvw, Mbf, wvbf, u);
  fused_kernel<<<1024, 512, LDS_BYTES, stream>>>(x, norm_w, norm_b, bvv, beta, Mbf, wvbf, u, out);
}